// Round 4
// baseline (375.589 us; speedup 1.0000x reference)
//
#include <hip/hip_runtime.h>
#include <math.h>

#define HD 128
#define GG 64
#define CSB 256   // colstat partial blocks

typedef __attribute__((ext_vector_type(8))) short short8;
typedef __attribute__((ext_vector_type(4))) float f32x4;
typedef __attribute__((ext_vector_type(2))) float f32x2;

__device__ __forceinline__ float leaky(float x, float s) { return x > 0.f ? x : s * x; }

__device__ __forceinline__ unsigned short bf16_of(float f) {
    union { float f; unsigned u; } v; v.f = f;
    unsigned r = v.u + 0x7fffu + ((v.u >> 16) & 1u);
    return (unsigned short)(r >> 16);
}
__device__ __forceinline__ float f_of_bf16(unsigned short u) {
    union { unsigned u; float f; } v; v.u = ((unsigned)u) << 16;
    return v.f;
}

// XOR-swizzled LDS addressing for the 128x128 bf16 W tile (16B chunks).
__device__ __forceinline__ int sw(int row, int chunk) {
    return row * 128 + ((chunk ^ (row & 15)) << 3);
}

// ---------------- init: W->Wt bf16 transposed + zero bucket counters ----------------
__global__ void k_init(const float* __restrict__ Ws, unsigned short* __restrict__ Wt,
                       int* __restrict__ bcnt) {
    int i = blockIdx.x * 256 + threadIdx.x;
    if (i < 3 * 16384) {
        int l = i >> 14, rem = i & 16383;
        int nn = rem >> 7, k = rem & 127;
        Wt[i] = bf16_of(Ws[l * 16384 + k * 128 + nn]);
    }
    if (i < 513) bcnt[i] = 0;
}

// ================= register-A + LDS-B MFMA GEMM, 64-row blocks =============
// (round-1 form: mfma(af, bfr); epilogue stores 2B/col with 4-line wave stores)

// ---- variant A: fp32 input (layer 0, no norm) ----
__global__ __launch_bounds__(256) void k_gemm_a32(
    const float* __restrict__ A, const unsigned short* __restrict__ Wt,
    const float* __restrict__ att_s, const float* __restrict__ att_d,
    unsigned short* __restrict__ hWb, float* __restrict__ a_s, float* __restrict__ a_d,
    int n) {
    __shared__ unsigned short Bs[128 * 128];
    const int tid = threadIdx.x;
    const int base = blockIdx.x * 64;

    const uint4* Wt4 = (const uint4*)Wt;
    uint4* Bs4 = (uint4*)Bs;
#pragma unroll
    for (int j = 0; j < 8; ++j) {
        int flat = tid + j * 256;
        int col = flat >> 4, c8 = flat & 15;
        Bs4[(col << 4) + (c8 ^ (col & 15))] = Wt4[flat];
    }

    const int wave = tid >> 6, lane = tid & 63;
    const int m16 = lane & 15, quad = lane >> 4;

    short8 af[4];
    {
        int row = base + wave * 16 + m16;
        row = (row < n) ? row : (n - 1);
        const float4* ap = (const float4*)(A + (size_t)row * 128);
#pragma unroll
        for (int kk = 0; kk < 4; ++kk) {
            float4 v0 = ap[kk * 8 + quad * 2];
            float4 v1 = ap[kk * 8 + quad * 2 + 1];
            union { short8 s; unsigned u[4]; } P;
            P.u[0] = (unsigned)bf16_of(v0.x) | ((unsigned)bf16_of(v0.y) << 16);
            P.u[1] = (unsigned)bf16_of(v0.z) | ((unsigned)bf16_of(v0.w) << 16);
            P.u[2] = (unsigned)bf16_of(v1.x) | ((unsigned)bf16_of(v1.y) << 16);
            P.u[3] = (unsigned)bf16_of(v1.z) | ((unsigned)bf16_of(v1.w) << 16);
            af[kk] = P.s;
        }
    }
    __syncthreads();

    f32x4 acc[8];
#pragma unroll
    for (int ct = 0; ct < 8; ++ct) acc[ct] = (f32x4){0.f, 0.f, 0.f, 0.f};
#pragma unroll
    for (int kk = 0; kk < 4; ++kk) {
#pragma unroll
        for (int ct = 0; ct < 8; ++ct) {
            short8 bfr = *(const short8*)&Bs[sw(ct * 16 + m16, kk * 4 + quad)];
            acc[ct] = __builtin_amdgcn_mfma_f32_16x16x32_bf16(af[kk], bfr, acc[ct], 0, 0, 0);
        }
    }

#pragma unroll
    for (int reg = 0; reg < 4; ++reg) {
        int gr = base + wave * 16 + quad * 4 + reg;
        bool ok = gr < n;
        unsigned short* rowp = hWb + (size_t)gr * 128 + m16;
        float s = 0.f, dd = 0.f;
#pragma unroll
        for (int ct = 0; ct < 8; ++ct) {
            float v = acc[ct][reg];
            int col = ct * 16 + m16;
            if (ok) rowp[ct * 16] = bf16_of(v);
            s = fmaf(v, att_s[col], s);
            dd = fmaf(v, att_d[col], dd);
        }
#pragma unroll
        for (int off = 1; off < 16; off <<= 1) {
            s += __shfl_xor(s, off, 64);
            dd += __shfl_xor(dd, off, 64);
        }
        if (m16 == 0 && ok) { a_s[gr] = s; a_d[gr] = dd; }
    }
}

// ---- variant B: bf16 input + GraphNorm affine + leaky (layers 1,2) ----
__global__ __launch_bounds__(256) void k_gemm_a16(
    const unsigned short* __restrict__ Ab, const unsigned short* __restrict__ Wt,
    const float* __restrict__ att_s, const float* __restrict__ att_d,
    const float* __restrict__ alpha, const float* __restrict__ beta,
    unsigned short* __restrict__ hWb, float* __restrict__ a_s, float* __restrict__ a_d,
    int n) {
    __shared__ unsigned short Bs[128 * 128];
    const int tid = threadIdx.x;
    const int base = blockIdx.x * 64;

    const uint4* Wt4 = (const uint4*)Wt;
    uint4* Bs4 = (uint4*)Bs;
#pragma unroll
    for (int j = 0; j < 8; ++j) {
        int flat = tid + j * 256;
        int col = flat >> 4, c8 = flat & 15;
        Bs4[(col << 4) + (c8 ^ (col & 15))] = Wt4[flat];
    }

    const int wave = tid >> 6, lane = tid & 63;
    const int m16 = lane & 15, quad = lane >> 4;
    const float4* al4 = (const float4*)alpha;
    const float4* be4 = (const float4*)beta;

    short8 af[4];
    {
        int row = base + wave * 16 + m16;
        row = (row < n) ? row : (n - 1);
        const uint4* ap = (const uint4*)(Ab + (size_t)row * 128);
#pragma unroll
        for (int kk = 0; kk < 4; ++kk) {
            uint4 raw = ap[kk * 4 + quad];
            int c4 = kk * 8 + quad * 2;
            float4 a0 = al4[c4], a1 = al4[c4 + 1];
            float4 b0 = be4[c4], b1 = be4[c4 + 1];
            float f0 = leaky(fmaf(f_of_bf16(raw.x & 0xffff), a0.x, b0.x), 0.01f);
            float f1 = leaky(fmaf(f_of_bf16(raw.x >> 16),    a0.y, b0.y), 0.01f);
            float f2 = leaky(fmaf(f_of_bf16(raw.y & 0xffff), a0.z, b0.z), 0.01f);
            float f3 = leaky(fmaf(f_of_bf16(raw.y >> 16),    a0.w, b0.w), 0.01f);
            float f4 = leaky(fmaf(f_of_bf16(raw.z & 0xffff), a1.x, b1.x), 0.01f);
            float f5 = leaky(fmaf(f_of_bf16(raw.z >> 16),    a1.y, b1.y), 0.01f);
            float f6 = leaky(fmaf(f_of_bf16(raw.w & 0xffff), a1.z, b1.z), 0.01f);
            float f7 = leaky(fmaf(f_of_bf16(raw.w >> 16),    a1.w, b1.w), 0.01f);
            union { short8 s; unsigned u[4]; } P;
            P.u[0] = (unsigned)bf16_of(f0) | ((unsigned)bf16_of(f1) << 16);
            P.u[1] = (unsigned)bf16_of(f2) | ((unsigned)bf16_of(f3) << 16);
            P.u[2] = (unsigned)bf16_of(f4) | ((unsigned)bf16_of(f5) << 16);
            P.u[3] = (unsigned)bf16_of(f6) | ((unsigned)bf16_of(f7) << 16);
            af[kk] = P.s;
        }
    }
    __syncthreads();

    f32x4 acc[8];
#pragma unroll
    for (int ct = 0; ct < 8; ++ct) acc[ct] = (f32x4){0.f, 0.f, 0.f, 0.f};
#pragma unroll
    for (int kk = 0; kk < 4; ++kk) {
#pragma unroll
        for (int ct = 0; ct < 8; ++ct) {
            short8 bfr = *(const short8*)&Bs[sw(ct * 16 + m16, kk * 4 + quad)];
            acc[ct] = __builtin_amdgcn_mfma_f32_16x16x32_bf16(af[kk], bfr, acc[ct], 0, 0, 0);
        }
    }

#pragma unroll
    for (int reg = 0; reg < 4; ++reg) {
        int gr = base + wave * 16 + quad * 4 + reg;
        bool ok = gr < n;
        unsigned short* rowp = hWb + (size_t)gr * 128 + m16;
        float s = 0.f, dd = 0.f;
#pragma unroll
        for (int ct = 0; ct < 8; ++ct) {
            float v = acc[ct][reg];
            int col = ct * 16 + m16;
            if (ok) rowp[ct * 16] = bf16_of(v);
            s = fmaf(v, att_s[col], s);
            dd = fmaf(v, att_d[col], dd);
        }
#pragma unroll
        for (int off = 1; off < 16; off <<= 1) {
            s += __shfl_xor(s, off, 64);
            dd += __shfl_xor(dd, off, 64);
        }
        if (m16 == 0 && ok) { a_s[gr] = s; a_d[gr] = dd; }
    }
}

// ================= bucketed CSR build (LDS atomics, compact writes) =============
// Buckets of 512 nodes: bucket b = dst >> 9, local id = dst & 511.
// ebuf packs (local << 18) | src  (valid for n <= 262144).

__global__ __launch_bounds__(256) void k_bcount(const int* __restrict__ dst,
                                                int* __restrict__ bcnt, int e) {
    __shared__ int lh[512];
    const int tid = threadIdx.x;
    for (int t = tid; t < 512; t += 256) lh[t] = 0;
    __syncthreads();
    for (int i = blockIdx.x * 256 + tid; i < e; i += gridDim.x * 256)
        atomicAdd(&lh[dst[i] >> 9], 1);
    __syncthreads();
    for (int t = tid; t < 512; t += 256)
        if (lh[t]) atomicAdd(&bcnt[t], lh[t]);
}

__global__ void k_bscan(const int* __restrict__ bcnt, int* __restrict__ bbase,
                        int* __restrict__ bcur, int* __restrict__ offs,
                        int nbk, int n, int e) {
    __shared__ int s[512];
    int t = threadIdx.x;
    int v = (t < nbk) ? bcnt[t] : 0;
    s[t] = v;
    __syncthreads();
    for (int off = 1; off < 512; off <<= 1) {
        int u = (t >= off) ? s[t - off] : 0;
        __syncthreads();
        s[t] += u;
        __syncthreads();
    }
    if (t < nbk) { bbase[t] = s[t] - v; bcur[t] = s[t] - v; }
    if (t == 0) { bbase[nbk] = e; offs[n] = e; }
}

__global__ __launch_bounds__(256) void k_part(const int* __restrict__ src,
                                              const int* __restrict__ dst,
                                              int* __restrict__ bcur,
                                              int* __restrict__ ebuf, int e) {
    __shared__ int lh[512];
    __shared__ int lbase[512];
    const int tid = threadIdx.x;
    const int chunk = (e + gridDim.x - 1) / gridDim.x;
    const int i0 = blockIdx.x * chunk;
    const int i1 = min(e, i0 + chunk);
    for (int t = tid; t < 512; t += 256) lh[t] = 0;
    __syncthreads();
    for (int i = i0 + tid; i < i1; i += 256) atomicAdd(&lh[dst[i] >> 9], 1);
    __syncthreads();
    for (int t = tid; t < 512; t += 256) {
        int c = lh[t];
        lbase[t] = c ? atomicAdd(&bcur[t], c) : 0;
    }
    __syncthreads();
    for (int t = tid; t < 512; t += 256) lh[t] = 0;
    __syncthreads();
    for (int i = i0 + tid; i < i1; i += 256) {
        int d = dst[i];
        int b = d >> 9;
        int p = lbase[b] + atomicAdd(&lh[b], 1);
        ebuf[p] = ((d & 511) << 18) | src[i];
    }
}

__global__ __launch_bounds__(256) void k_bscatter(const int* __restrict__ ebuf,
                                                  const int* __restrict__ bbase,
                                                  int* __restrict__ offs,
                                                  int* __restrict__ esrc, int n) {
    const int b = blockIdx.x;
    const int tid = threadIdx.x;
    const int nb0 = b << 9;
    const int e0 = bbase[b], e1 = bbase[b + 1];
    __shared__ int cnt[512];
    __shared__ int sc[512];
    __shared__ int pos[512];
    for (int t = tid; t < 512; t += 256) cnt[t] = 0;
    __syncthreads();
    for (int i = e0 + tid; i < e1; i += 256) atomicAdd(&cnt[ebuf[i] >> 18], 1);
    __syncthreads();
    for (int t = tid; t < 512; t += 256) sc[t] = cnt[t];
    __syncthreads();
    for (int off = 1; off < 512; off <<= 1) {
        int t0 = tid, t1 = tid + 256;
        int v0 = (t0 >= off) ? sc[t0 - off] : 0;
        int v1 = sc[t1 - off];
        __syncthreads();
        sc[t0] += v0;
        sc[t1] += v1;
        __syncthreads();
    }
    for (int t = tid; t < 512; t += 256) pos[t] = e0 + sc[t] - cnt[t];
    __syncthreads();
    for (int t = tid; t < 512; t += 256) {
        int node = nb0 + t;
        if (node < n) offs[node] = pos[t];
    }
    __syncthreads();
    for (int i = e0 + tid; i < e1; i += 256) {
        int v = ebuf[i];
        int l = v >> 18;
        int p = atomicAdd(&pos[l], 1);
        esrc[p] = v & 0x3FFFF;
    }
}

// ---------------- fused attention softmax + aggregation -> bf16 h ------------------
// One 16-lane group per destination node (4 nodes/wave, 16 nodes/block), sequential
// node order. Depth-4 software pipeline: 4 hW-row gathers in flight per group
// (named registers r0..r3 -> no scratch). Summation order identical to depth-1.

#define AGG_ACC(r, ex) do {                                                   \
    const f32x2 exv_ = {(ex), (ex)};                                          \
    f32x2 v_;                                                                 \
    v_.x = f_of_bf16((r).x & 0xffff); v_.y = f_of_bf16((r).x >> 16);          \
    acc0 = __builtin_elementwise_fma(exv_, v_, acc0);                         \
    v_.x = f_of_bf16((r).y & 0xffff); v_.y = f_of_bf16((r).y >> 16);          \
    acc1 = __builtin_elementwise_fma(exv_, v_, acc1);                         \
    v_.x = f_of_bf16((r).z & 0xffff); v_.y = f_of_bf16((r).z >> 16);          \
    acc2 = __builtin_elementwise_fma(exv_, v_, acc2);                         \
    v_.x = f_of_bf16((r).w & 0xffff); v_.y = f_of_bf16((r).w >> 16);          \
    acc3 = __builtin_elementwise_fma(exv_, v_, acc3);                         \
} while (0)

#define AGG_SLOT(rk, ask, off) do {                                           \
    int idx_ = p + (off); idx_ = (idx_ <= last) ? idx_ : last;                \
    int sn_ = esrc[idx_];                                                     \
    uint4 rn_ = hW8[(size_t)sn_ * 16 + l16];                                  \
    float an_ = a_s[sn_];                                                     \
    float ex_ = __expf(leaky((ask) + ad, 0.2f));                              \
    ssum += ex_;                                                              \
    AGG_ACC(rk, ex_);                                                         \
    rk = rn_; ask = an_;                                                      \
} while (0)

__global__ __launch_bounds__(256) void k_agg(const unsigned short* __restrict__ hWb,
                                             const int* __restrict__ offs,
                                             const int* __restrict__ esrc,
                                             const float* __restrict__ a_s,
                                             const float* __restrict__ a_d,
                                             const float* __restrict__ bias,
                                             unsigned short* __restrict__ hb, int n) {
    const int tid = threadIdx.x;
    const int l16 = tid & 15;
    const int d = blockIdx.x * 16 + (tid >> 4);   // one node per 16-lane group
    if (d >= n) return;
    const int p0 = offs[d], p1 = offs[d + 1];
    const float ad = a_d[d];
    const uint4* hW8 = (const uint4*)hWb;

    f32x2 acc0 = {0.f, 0.f}, acc1 = {0.f, 0.f}, acc2 = {0.f, 0.f}, acc3 = {0.f, 0.f};
    float ssum = 0.f;

    if (p0 < p1) {
        const int last = p1 - 1;
        // prologue: fill 4 pipeline slots (clamped to last edge)
        int i1 = (p0 + 1 <= last) ? p0 + 1 : last;
        int i2 = (p0 + 2 <= last) ? p0 + 2 : last;
        int i3 = (p0 + 3 <= last) ? p0 + 3 : last;
        int s0 = esrc[p0], s1 = esrc[i1], s2 = esrc[i2], s3 = esrc[i3];
        uint4 r0 = hW8[(size_t)s0 * 16 + l16];
        uint4 r1 = hW8[(size_t)s1 * 16 + l16];
        uint4 r2 = hW8[(size_t)s2 * 16 + l16];
        uint4 r3 = hW8[(size_t)s3 * 16 + l16];
        float as0 = a_s[s0], as1 = a_s[s1], as2 = a_s[s2], as3 = a_s[s3];

        for (int p = p0; p < p1; p += 4) {
            AGG_SLOT(r0, as0, 4);
            if (p + 1 < p1) AGG_SLOT(r1, as1, 5);
            if (p + 2 < p1) AGG_SLOT(r2, as2, 6);
            if (p + 3 < p1) AGG_SLOT(r3, as3, 7);
        }
    }

    const float inv = 1.f / (ssum + 1e-16f);
    const float4* b4p = (const float4*)bias;
    const float4 bb0 = b4p[l16 * 2], bb1 = b4p[l16 * 2 + 1];
    uint4 o;
    o.x = (unsigned)bf16_of(fmaf(acc0.x, inv, bb0.x)) |
          ((unsigned)bf16_of(fmaf(acc0.y, inv, bb0.y)) << 16);
    o.y = (unsigned)bf16_of(fmaf(acc1.x, inv, bb0.z)) |
          ((unsigned)bf16_of(fmaf(acc1.y, inv, bb0.w)) << 16);
    o.z = (unsigned)bf16_of(fmaf(acc2.x, inv, bb1.x)) |
          ((unsigned)bf16_of(fmaf(acc2.y, inv, bb1.y)) << 16);
    o.w = (unsigned)bf16_of(fmaf(acc3.x, inv, bb1.z)) |
          ((unsigned)bf16_of(fmaf(acc3.y, inv, bb1.w)) << 16);
    ((uint4*)hb)[(size_t)d * 16 + l16] = o;
}

// ---------------- GraphNorm stats: partials only (no fence, no tail) ----------------
__global__ __launch_bounds__(256) void k_colstat6(const unsigned short* __restrict__ hb,
                                                  float* __restrict__ part, int n) {
    const uint4* h8 = (const uint4*)hb;    // 16 uint4 per 128-col row
    const int tid = threadIdx.x;
    const int total = n * 16;
    float s[8] = {0.f,0.f,0.f,0.f,0.f,0.f,0.f,0.f};
    float q[8] = {0.f,0.f,0.f,0.f,0.f,0.f,0.f,0.f};
    for (int i = blockIdx.x * 256 + tid; i < total; i += CSB * 256) {
        uint4 raw = h8[i];
        float v0 = f_of_bf16(raw.x & 0xffff), v1 = f_of_bf16(raw.x >> 16);
        float v2 = f_of_bf16(raw.y & 0xffff), v3 = f_of_bf16(raw.y >> 16);
        float v4 = f_of_bf16(raw.z & 0xffff), v5 = f_of_bf16(raw.z >> 16);
        float v6 = f_of_bf16(raw.w & 0xffff), v7 = f_of_bf16(raw.w >> 16);
        s[0] += v0; q[0] = fmaf(v0, v0, q[0]);
        s[1] += v1; q[1] = fmaf(v1, v1, q[1]);
        s[2] += v2; q[2] = fmaf(v2, v2, q[2]);
        s[3] += v3; q[3] = fmaf(v3, v3, q[3]);
        s[4] += v4; q[4] = fmaf(v4, v4, q[4]);
        s[5] += v5; q[5] = fmaf(v5, v5, q[5]);
        s[6] += v6; q[6] = fmaf(v6, v6, q[6]);
        s[7] += v7; q[7] = fmaf(v7, v7, q[7]);
    }
    __shared__ float ss[256][9];   // pad 9 -> conflict-free
    __shared__ float sq[256][9];
#pragma unroll
    for (int k = 0; k < 8; ++k) { ss[tid][k] = s[k]; sq[tid][k] = q[k]; }
    __syncthreads();
    if (tid < 128) {
        int c = tid >> 3, k = tid & 7;     // col = c*8 + k = tid
        float S = 0.f, Q = 0.f;
#pragma unroll
        for (int g = 0; g < 16; ++g) {
            S += ss[g * 16 + c][k];
            Q += sq[g * 16 + c][k];
        }
        part[blockIdx.x * 256 + tid] = S;
        part[blockIdx.x * 256 + 128 + tid] = Q;
    }
}

// ---------------- reduce partials + alpha/beta (separate launch = free visibility) --
__global__ __launch_bounds__(256) void k_colfin(const float* __restrict__ part,
                                                const float* __restrict__ w,
                                                const float* __restrict__ bb,
                                                const float* __restrict__ ms,
                                                float* __restrict__ alpha,
                                                float* __restrict__ beta, float inv_n) {
    int tid = threadIdx.x;
    float a0 = 0.f, a1 = 0.f, a2 = 0.f, a3 = 0.f;
    for (int b = 0; b < CSB; b += 4) {
        a0 += part[(b + 0) * 256 + tid];
        a1 += part[(b + 1) * 256 + tid];
        a2 += part[(b + 2) * 256 + tid];
        a3 += part[(b + 3) * 256 + tid];
    }
    __shared__ float fin[256];
    fin[tid] = (a0 + a1) + (a2 + a3);
    __syncthreads();
    if (tid < 128) {
        float mean = fin[tid] * inv_n;
        float ex2 = fin[128 + tid] * inv_n;
        float m2 = mean * ms[tid];
        float var = ex2 - 2.f * m2 * mean + m2 * m2;
        float a = w[tid] * rsqrtf(var + 1e-5f);
        alpha[tid] = a;
        beta[tid] = bb[tid] - m2 * a;
    }
}

// ---------------- global_add_pool: 4 blocks/graph, binary search, no atomics -------
__device__ __forceinline__ int lower_bound_i(const int* __restrict__ a, int n, int key) {
    int lo = 0, hi = n;
    while (lo < hi) {
        int mid = (lo + hi) >> 1;
        if (a[mid] < key) lo = mid + 1; else hi = mid;
    }
    return lo;
}

__global__ __launch_bounds__(256) void k_pool(const unsigned short* __restrict__ hb,
                                              const int* __restrict__ batch,
                                              float* __restrict__ pooled4, int n) {
    int g = blockIdx.x >> 2, t4 = blockIdx.x & 3;
    int lo = lower_bound_i(batch, n, g);
    int hi = lower_bound_i(batch, n, g + 1);
    int len = hi - lo;
    int q = (len + 3) >> 2;
    int r0 = lo + t4 * q;
    int r1 = min(r0 + q, hi);
    int c4 = threadIdx.x & 31, rg = threadIdx.x >> 5;
    const ushort4* h4 = (const ushort4*)hb;
    float4 acc = make_float4(0.f, 0.f, 0.f, 0.f);
    for (int r = r0 + rg; r < r1; r += 8) {
        ushort4 hv = h4[(size_t)r * 32 + c4];
        acc.x += f_of_bf16(hv.x);
        acc.y += f_of_bf16(hv.y);
        acc.z += f_of_bf16(hv.z);
        acc.w += f_of_bf16(hv.w);
    }
    __shared__ float4 sred[256];
    sred[threadIdx.x] = acc;
    __syncthreads();
    if (threadIdx.x < 32) {
        float4 S = sred[threadIdx.x];
#pragma unroll
        for (int k = 1; k < 8; ++k) {
            float4 a = sred[threadIdx.x + 32 * k];
            S.x += a.x; S.y += a.y; S.z += a.z; S.w += a.w;
        }
        ((float4*)pooled4)[(t4 * GG + g) * 32 + threadIdx.x] = S;
    }
}

// ---------------- final MLP (sums the 4 pool partials) ----------------
__global__ __launch_bounds__(128) void k_mlp(const float* __restrict__ pooled4,
                                             const float* __restrict__ W1,
                                             const float* __restrict__ b1,
                                             const float* __restrict__ W2,
                                             const float* __restrict__ b2,
                                             float* __restrict__ out) {
    __shared__ float pr[HD];
    __shared__ float zs[HD];
    int g = blockIdx.x, t = threadIdx.x;
    float pv = 0.f;
#pragma unroll
    for (int k = 0; k < 4; ++k) pv += pooled4[(k * GG + g) * HD + t];
    pr[t] = pv;
    __syncthreads();
    float acc = b1[t];
#pragma unroll 8
    for (int k = 0; k < HD; ++k) acc = fmaf(pr[k], W1[k * HD + t], acc);
    zs[t] = leaky(acc, 0.01f);
    __syncthreads();
    if (t < 64) {
        float a2 = b2[t];
#pragma unroll 8
        for (int k = 0; k < HD; ++k) a2 = fmaf(zs[k], W2[k * 64 + t], a2);
        out[g * 64 + t] = a2;
    }
}

extern "C" void kernel_launch(void* const* d_in, const int* in_sizes, int n_in,
                              void* d_out, int out_size, void* d_ws, size_t ws_size,
                              hipStream_t stream) {
    const float* x        = (const float*)d_in[0];
    const int*   ei       = (const int*)d_in[1];
    const int*   batch    = (const int*)d_in[2];
    const float* Ws       = (const float*)d_in[3];
    const float* att_src  = (const float*)d_in[4];
    const float* att_dst  = (const float*)d_in[5];
    const float* conv_bias= (const float*)d_in[6];
    const float* gn_w     = (const float*)d_in[7];
    const float* gn_b     = (const float*)d_in[8];
    const float* gn_ms    = (const float*)d_in[9];
    const float* W1       = (const float*)d_in[10];
    const float* b1       = (const float*)d_in[11];
    const float* W2       = (const float*)d_in[12];
    const float* b2       = (const float*)d_in[13];
    float* out = (float*)d_out;

    const int n = in_sizes[2];       // 100000
    const int e = in_sizes[1] / 2;   // 600000
    const int* src = ei;
    const int* dst = ei + e;
    const int nbk = (n + 511) >> 9;  // 512-node buckets (n <= 262144 for ebuf packing)

    char* ws = (char*)d_ws;
    unsigned short* hWb = (unsigned short*)ws;                    // n*128 bf16
    unsigned short* hb  = hWb + (size_t)n * HD;                   // n*128 bf16
    float* a_s    = (float*)(hb + (size_t)n * HD);                // n
    float* a_d    = a_s + n;                                      // n
    float* alpha  = a_d + n;                                      // 128
    float* beta   = alpha + HD;                                   // 128
    float* pooled4= beta + HD;                                    // 4*GG*128
    float* part   = pooled4 + 4 * GG * HD;                        // CSB*256
    unsigned short* Wt = (unsigned short*)(part + CSB * 256);     // 3*128*128
    int* offs     = (int*)(Wt + 3 * 16384);                       // n+1
    int* esrc     = offs + n + 1;                                 // e
    int* ebuf     = esrc + e;                                     // e
    int* bcnt     = ebuf + e;                                     // 513
    int* bbase    = bcnt + 513;                                   // 514
    int* bcur     = bbase + 514;                                  // 513

    // ---- init (weights->bf16 transposed + zero bucket counters) ----
    k_init<<<192, 256, 0, stream>>>(Ws, Wt, bcnt);
    // ---- bucketed CSR build ----
    k_bcount<<<256, 256, 0, stream>>>(dst, bcnt, e);
    k_bscan<<<1, 512, 0, stream>>>(bcnt, bbase, bcur, offs, nbk, n, e);
    k_part<<<256, 256, 0, stream>>>(src, dst, bcur, ebuf, e);
    k_bscatter<<<nbk, 256, 0, stream>>>(ebuf, bbase, offs, esrc, n);

    // ---- GAT layers ----
    for (int l = 0; l < 3; ++l) {
        if (l == 0) {
            k_gemm_a32<<<(n + 63) / 64, 256, 0, stream>>>(
                x, Wt, att_src, att_dst, hWb, a_s, a_d, n);
        } else {
            k_gemm_a16<<<(n + 63) / 64, 256, 0, stream>>>(
                hb, Wt + l * 16384, att_src + l * HD, att_dst + l * HD,
                alpha, beta, hWb, a_s, a_d, n);
        }
        k_agg<<<(n + 15) / 16, 256, 0, stream>>>(hWb, offs, esrc, a_s, a_d,
                                                 conv_bias + l * HD, hb, n);
        if (l < 2) {
            k_colstat6<<<CSB, 256, 0, stream>>>(hb, part, n);
            k_colfin<<<1, 256, 0, stream>>>(part, gn_w + l * HD, gn_b + l * HD,
                                            gn_ms + l * HD, alpha, beta, 1.0f / n);
        }
    }

    // ---- pool + MLP ----
    k_pool<<<4 * GG, 256, 0, stream>>>(hb, batch, pooled4, n);
    k_mlp<<<GG, HD, 0, stream>>>(pooled4, W1, b1, W2, b2, out);
}

// Round 5
// 354.327 us; speedup vs baseline: 1.0600x; 1.0600x over previous
//
#include <hip/hip_runtime.h>
#include <math.h>

#define HD 128
#define GG 64
#define CSB 256   // colstat partial slots

typedef __attribute__((ext_vector_type(8))) short short8;
typedef __attribute__((ext_vector_type(4))) float f32x4;
typedef __attribute__((ext_vector_type(2))) float f32x2;

__device__ __forceinline__ float leaky(float x, float s) { return x > 0.f ? x : s * x; }

__device__ __forceinline__ unsigned short bf16_of(float f) {
    union { float f; unsigned u; } v; v.f = f;
    unsigned r = v.u + 0x7fffu + ((v.u >> 16) & 1u);
    return (unsigned short)(r >> 16);
}
__device__ __forceinline__ float f_of_bf16(unsigned short u) {
    union { unsigned u; float f; } v; v.u = ((unsigned)u) << 16;
    return v.f;
}

// XOR-swizzled LDS addressing for the 128x128 bf16 W tile (16B chunks).
__device__ __forceinline__ int sw(int row, int chunk) {
    return row * 128 + ((chunk ^ (row & 15)) << 3);
}

// ---------------- init: W->Wt bf16 transposed + zero bucket counters + part ---------
__global__ void k_init(const float* __restrict__ Ws, unsigned short* __restrict__ Wt,
                       int* __restrict__ bcnt, float* __restrict__ part) {
    int i = blockIdx.x * 256 + threadIdx.x;   // grid 512*256 = 131072
    if (i < 3 * 16384) {
        int l = i >> 14, rem = i & 16383;
        int nn = rem >> 7, k = rem & 127;
        Wt[i] = bf16_of(Ws[l * 16384 + k * 128 + nn]);
    }
    if (i < 513) bcnt[i] = 0;
    part[i] = 0.f;                            // 2*CSB*256 = 131072 floats exactly
}

// ================= register-A + LDS-B MFMA GEMM, 64-row blocks =============
// (round-1 form: mfma(af, bfr); per-reg epilogue with 16-lane shuffle att dots)

// ---- variant A: fp32 input (layer 0, no norm) ----
__global__ __launch_bounds__(256) void k_gemm_a32(
    const float* __restrict__ A, const unsigned short* __restrict__ Wt,
    const float* __restrict__ att_s, const float* __restrict__ att_d,
    unsigned short* __restrict__ hWb, float* __restrict__ a_s, float* __restrict__ a_d,
    int n) {
    __shared__ unsigned short Bs[128 * 128];
    const int tid = threadIdx.x;
    const int base = blockIdx.x * 64;

    const uint4* Wt4 = (const uint4*)Wt;
    uint4* Bs4 = (uint4*)Bs;
#pragma unroll
    for (int j = 0; j < 8; ++j) {
        int flat = tid + j * 256;
        int col = flat >> 4, c8 = flat & 15;
        Bs4[(col << 4) + (c8 ^ (col & 15))] = Wt4[flat];
    }

    const int wave = tid >> 6, lane = tid & 63;
    const int m16 = lane & 15, quad = lane >> 4;

    short8 af[4];
    {
        int row = base + wave * 16 + m16;
        row = (row < n) ? row : (n - 1);
        const float4* ap = (const float4*)(A + (size_t)row * 128);
#pragma unroll
        for (int kk = 0; kk < 4; ++kk) {
            float4 v0 = ap[kk * 8 + quad * 2];
            float4 v1 = ap[kk * 8 + quad * 2 + 1];
            union { short8 s; unsigned u[4]; } P;
            P.u[0] = (unsigned)bf16_of(v0.x) | ((unsigned)bf16_of(v0.y) << 16);
            P.u[1] = (unsigned)bf16_of(v0.z) | ((unsigned)bf16_of(v0.w) << 16);
            P.u[2] = (unsigned)bf16_of(v1.x) | ((unsigned)bf16_of(v1.y) << 16);
            P.u[3] = (unsigned)bf16_of(v1.z) | ((unsigned)bf16_of(v1.w) << 16);
            af[kk] = P.s;
        }
    }
    __syncthreads();

    f32x4 acc[8];
#pragma unroll
    for (int ct = 0; ct < 8; ++ct) acc[ct] = (f32x4){0.f, 0.f, 0.f, 0.f};
#pragma unroll
    for (int kk = 0; kk < 4; ++kk) {
#pragma unroll
        for (int ct = 0; ct < 8; ++ct) {
            short8 bfr = *(const short8*)&Bs[sw(ct * 16 + m16, kk * 4 + quad)];
            acc[ct] = __builtin_amdgcn_mfma_f32_16x16x32_bf16(af[kk], bfr, acc[ct], 0, 0, 0);
        }
    }

#pragma unroll
    for (int reg = 0; reg < 4; ++reg) {
        int gr = base + wave * 16 + quad * 4 + reg;
        bool ok = gr < n;
        unsigned short* rowp = hWb + (size_t)gr * 128 + m16;
        float s = 0.f, dd = 0.f;
#pragma unroll
        for (int ct = 0; ct < 8; ++ct) {
            float v = acc[ct][reg];
            int col = ct * 16 + m16;
            if (ok) rowp[ct * 16] = bf16_of(v);
            s = fmaf(v, att_s[col], s);
            dd = fmaf(v, att_d[col], dd);
        }
#pragma unroll
        for (int off = 1; off < 16; off <<= 1) {
            s += __shfl_xor(s, off, 64);
            dd += __shfl_xor(dd, off, 64);
        }
        if (m16 == 0 && ok) { a_s[gr] = s; a_d[gr] = dd; }
    }
}

// ---- variant B: bf16 input + GraphNorm affine + leaky (layers 1,2) ----
__global__ __launch_bounds__(256) void k_gemm_a16(
    const unsigned short* __restrict__ Ab, const unsigned short* __restrict__ Wt,
    const float* __restrict__ att_s, const float* __restrict__ att_d,
    const float* __restrict__ alpha, const float* __restrict__ beta,
    unsigned short* __restrict__ hWb, float* __restrict__ a_s, float* __restrict__ a_d,
    int n) {
    __shared__ unsigned short Bs[128 * 128];
    const int tid = threadIdx.x;
    const int base = blockIdx.x * 64;

    const uint4* Wt4 = (const uint4*)Wt;
    uint4* Bs4 = (uint4*)Bs;
#pragma unroll
    for (int j = 0; j < 8; ++j) {
        int flat = tid + j * 256;
        int col = flat >> 4, c8 = flat & 15;
        Bs4[(col << 4) + (c8 ^ (col & 15))] = Wt4[flat];
    }

    const int wave = tid >> 6, lane = tid & 63;
    const int m16 = lane & 15, quad = lane >> 4;
    const float4* al4 = (const float4*)alpha;
    const float4* be4 = (const float4*)beta;

    short8 af[4];
    {
        int row = base + wave * 16 + m16;
        row = (row < n) ? row : (n - 1);
        const uint4* ap = (const uint4*)(Ab + (size_t)row * 128);
#pragma unroll
        for (int kk = 0; kk < 4; ++kk) {
            uint4 raw = ap[kk * 4 + quad];
            int c4 = kk * 8 + quad * 2;
            float4 a0 = al4[c4], a1 = al4[c4 + 1];
            float4 b0 = be4[c4], b1 = be4[c4 + 1];
            float f0 = leaky(fmaf(f_of_bf16(raw.x & 0xffff), a0.x, b0.x), 0.01f);
            float f1 = leaky(fmaf(f_of_bf16(raw.x >> 16),    a0.y, b0.y), 0.01f);
            float f2 = leaky(fmaf(f_of_bf16(raw.y & 0xffff), a0.z, b0.z), 0.01f);
            float f3 = leaky(fmaf(f_of_bf16(raw.y >> 16),    a0.w, b0.w), 0.01f);
            float f4 = leaky(fmaf(f_of_bf16(raw.z & 0xffff), a1.x, b1.x), 0.01f);
            float f5 = leaky(fmaf(f_of_bf16(raw.z >> 16),    a1.y, b1.y), 0.01f);
            float f6 = leaky(fmaf(f_of_bf16(raw.w & 0xffff), a1.z, b1.z), 0.01f);
            float f7 = leaky(fmaf(f_of_bf16(raw.w >> 16),    a1.w, b1.w), 0.01f);
            union { short8 s; unsigned u[4]; } P;
            P.u[0] = (unsigned)bf16_of(f0) | ((unsigned)bf16_of(f1) << 16);
            P.u[1] = (unsigned)bf16_of(f2) | ((unsigned)bf16_of(f3) << 16);
            P.u[2] = (unsigned)bf16_of(f4) | ((unsigned)bf16_of(f5) << 16);
            P.u[3] = (unsigned)bf16_of(f6) | ((unsigned)bf16_of(f7) << 16);
            af[kk] = P.s;
        }
    }
    __syncthreads();

    f32x4 acc[8];
#pragma unroll
    for (int ct = 0; ct < 8; ++ct) acc[ct] = (f32x4){0.f, 0.f, 0.f, 0.f};
#pragma unroll
    for (int kk = 0; kk < 4; ++kk) {
#pragma unroll
        for (int ct = 0; ct < 8; ++ct) {
            short8 bfr = *(const short8*)&Bs[sw(ct * 16 + m16, kk * 4 + quad)];
            acc[ct] = __builtin_amdgcn_mfma_f32_16x16x32_bf16(af[kk], bfr, acc[ct], 0, 0, 0);
        }
    }

#pragma unroll
    for (int reg = 0; reg < 4; ++reg) {
        int gr = base + wave * 16 + quad * 4 + reg;
        bool ok = gr < n;
        unsigned short* rowp = hWb + (size_t)gr * 128 + m16;
        float s = 0.f, dd = 0.f;
#pragma unroll
        for (int ct = 0; ct < 8; ++ct) {
            float v = acc[ct][reg];
            int col = ct * 16 + m16;
            if (ok) rowp[ct * 16] = bf16_of(v);
            s = fmaf(v, att_s[col], s);
            dd = fmaf(v, att_d[col], dd);
        }
#pragma unroll
        for (int off = 1; off < 16; off <<= 1) {
            s += __shfl_xor(s, off, 64);
            dd += __shfl_xor(dd, off, 64);
        }
        if (m16 == 0 && ok) { a_s[gr] = s; a_d[gr] = dd; }
    }
}

// ================= bucketed CSR build (LDS atomics, compact writes) =============
// Buckets of 512 nodes: bucket b = dst >> 9, local id = dst & 511.
// ebuf packs (local << 18) | src  (valid for n <= 262144).

__global__ __launch_bounds__(256) void k_bcount(const int* __restrict__ dst,
                                                int* __restrict__ bcnt, int e) {
    __shared__ int lh[512];
    const int tid = threadIdx.x;
    for (int t = tid; t < 512; t += 256) lh[t] = 0;
    __syncthreads();
    for (int i = blockIdx.x * 256 + tid; i < e; i += gridDim.x * 256)
        atomicAdd(&lh[dst[i] >> 9], 1);
    __syncthreads();
    for (int t = tid; t < 512; t += 256)
        if (lh[t]) atomicAdd(&bcnt[t], lh[t]);
}

__global__ void k_bscan(const int* __restrict__ bcnt, int* __restrict__ bbase,
                        int* __restrict__ bcur, int* __restrict__ offs,
                        int nbk, int n, int e) {
    __shared__ int s[512];
    int t = threadIdx.x;
    int v = (t < nbk) ? bcnt[t] : 0;
    s[t] = v;
    __syncthreads();
    for (int off = 1; off < 512; off <<= 1) {
        int u = (t >= off) ? s[t - off] : 0;
        __syncthreads();
        s[t] += u;
        __syncthreads();
    }
    if (t < nbk) { bbase[t] = s[t] - v; bcur[t] = s[t] - v; }
    if (t == 0) { bbase[nbk] = e; offs[n] = e; }
}

__global__ __launch_bounds__(256) void k_part(const int* __restrict__ src,
                                              const int* __restrict__ dst,
                                              int* __restrict__ bcur,
                                              int* __restrict__ ebuf, int e) {
    __shared__ int lh[512];
    __shared__ int lbase[512];
    const int tid = threadIdx.x;
    const int chunk = (e + gridDim.x - 1) / gridDim.x;
    const int i0 = blockIdx.x * chunk;
    const int i1 = min(e, i0 + chunk);
    for (int t = tid; t < 512; t += 256) lh[t] = 0;
    __syncthreads();
    for (int i = i0 + tid; i < i1; i += 256) atomicAdd(&lh[dst[i] >> 9], 1);
    __syncthreads();
    for (int t = tid; t < 512; t += 256) {
        int c = lh[t];
        lbase[t] = c ? atomicAdd(&bcur[t], c) : 0;
    }
    __syncthreads();
    for (int t = tid; t < 512; t += 256) lh[t] = 0;
    __syncthreads();
    for (int i = i0 + tid; i < i1; i += 256) {
        int d = dst[i];
        int b = d >> 9;
        int p = lbase[b] + atomicAdd(&lh[b], 1);
        ebuf[p] = ((d & 511) << 18) | src[i];
    }
}

__global__ __launch_bounds__(256) void k_bscatter(const int* __restrict__ ebuf,
                                                  const int* __restrict__ bbase,
                                                  int* __restrict__ offs,
                                                  int* __restrict__ esrc, int n) {
    const int b = blockIdx.x;
    const int tid = threadIdx.x;
    const int nb0 = b << 9;
    const int e0 = bbase[b], e1 = bbase[b + 1];
    __shared__ int cnt[512];
    __shared__ int sc[512];
    __shared__ int pos[512];
    for (int t = tid; t < 512; t += 256) cnt[t] = 0;
    __syncthreads();
    for (int i = e0 + tid; i < e1; i += 256) atomicAdd(&cnt[ebuf[i] >> 18], 1);
    __syncthreads();
    for (int t = tid; t < 512; t += 256) sc[t] = cnt[t];
    __syncthreads();
    for (int off = 1; off < 512; off <<= 1) {
        int t0 = tid, t1 = tid + 256;
        int v0 = (t0 >= off) ? sc[t0 - off] : 0;
        int v1 = sc[t1 - off];
        __syncthreads();
        sc[t0] += v0;
        sc[t1] += v1;
        __syncthreads();
    }
    for (int t = tid; t < 512; t += 256) pos[t] = e0 + sc[t] - cnt[t];
    __syncthreads();
    for (int t = tid; t < 512; t += 256) {
        int node = nb0 + t;
        if (node < n) offs[node] = pos[t];
    }
    __syncthreads();
    for (int i = e0 + tid; i < e1; i += 256) {
        int v = ebuf[i];
        int l = v >> 18;
        int p = atomicAdd(&pos[l], 1);
        esrc[p] = v & 0x3FFFF;
    }
}

// ---------------- fused attention softmax + aggregation -> bf16 h ------------------
// One 16-lane group per destination node (4 nodes/wave, 16 nodes/block), sequential
// node order. R1 depth-1 pipeline (validated best). Fused GraphNorm stats tail:
// when part != nullptr, block-reduce col sums/sumsq of the 16 output rows (LDS
// transpose-reduce, colstat layout) and atomicAdd into part[slot*256 + {col,128+col}].
__global__ __launch_bounds__(256) void k_agg(const unsigned short* __restrict__ hWb,
                                             const int* __restrict__ offs,
                                             const int* __restrict__ esrc,
                                             const float* __restrict__ a_s,
                                             const float* __restrict__ a_d,
                                             const float* __restrict__ bias,
                                             unsigned short* __restrict__ hb,
                                             float* __restrict__ part, int n) {
    __shared__ float ss[256][9];
    __shared__ float sq[256][9];
    const int tid = threadIdx.x;
    const int l16 = tid & 15;
    const int d = blockIdx.x * 16 + (tid >> 4);   // one node per 16-lane group
    const bool active = d < n;

    f32x2 acc0 = {0.f, 0.f}, acc1 = {0.f, 0.f}, acc2 = {0.f, 0.f}, acc3 = {0.f, 0.f};
    float ssum = 0.f;
    float h0 = 0.f, h1 = 0.f, h2 = 0.f, h3 = 0.f, h4 = 0.f, h5 = 0.f, h6 = 0.f, h7 = 0.f;

    if (active) {
        const int p0 = offs[d], p1 = offs[d + 1];
        const float ad = a_d[d];
        const uint4* hW8 = (const uint4*)hWb;

        // 1-deep software pipeline: row/score of edge p prefetched during edge p-1
        int s_cur = (p0 < p1) ? esrc[p0] : 0;
        uint4 raw = hW8[(size_t)s_cur * 16 + l16];
        float as_cur = a_s[s_cur];
        for (int p = p0; p < p1; ++p) {
            const uint4 r = raw;
            const float e = leaky(as_cur + ad, 0.2f);
            const int pn = (p + 1 < p1) ? p + 1 : p;
            const int s_nxt = esrc[pn];
            raw = hW8[(size_t)s_nxt * 16 + l16];
            as_cur = a_s[s_nxt];

            const float ex = __expf(e);
            ssum += ex;
            const f32x2 exv = {ex, ex};
            f32x2 v;
            v.x = f_of_bf16(r.x & 0xffff); v.y = f_of_bf16(r.x >> 16);
            acc0 = __builtin_elementwise_fma(exv, v, acc0);
            v.x = f_of_bf16(r.y & 0xffff); v.y = f_of_bf16(r.y >> 16);
            acc1 = __builtin_elementwise_fma(exv, v, acc1);
            v.x = f_of_bf16(r.z & 0xffff); v.y = f_of_bf16(r.z >> 16);
            acc2 = __builtin_elementwise_fma(exv, v, acc2);
            v.x = f_of_bf16(r.w & 0xffff); v.y = f_of_bf16(r.w >> 16);
            acc3 = __builtin_elementwise_fma(exv, v, acc3);
        }

        const float inv = 1.f / (ssum + 1e-16f);
        const float4* b4p = (const float4*)bias;
        const float4 bb0 = b4p[l16 * 2], bb1 = b4p[l16 * 2 + 1];
        h0 = fmaf(acc0.x, inv, bb0.x); h1 = fmaf(acc0.y, inv, bb0.y);
        h2 = fmaf(acc1.x, inv, bb0.z); h3 = fmaf(acc1.y, inv, bb0.w);
        h4 = fmaf(acc2.x, inv, bb1.x); h5 = fmaf(acc2.y, inv, bb1.y);
        h6 = fmaf(acc3.x, inv, bb1.z); h7 = fmaf(acc3.y, inv, bb1.w);
        uint4 o;
        o.x = (unsigned)bf16_of(h0) | ((unsigned)bf16_of(h1) << 16);
        o.y = (unsigned)bf16_of(h2) | ((unsigned)bf16_of(h3) << 16);
        o.z = (unsigned)bf16_of(h4) | ((unsigned)bf16_of(h5) << 16);
        o.w = (unsigned)bf16_of(h6) | ((unsigned)bf16_of(h7) << 16);
        ((uint4*)hb)[(size_t)d * 16 + l16] = o;
    }

    if (part != nullptr) {
        // colstat layout: thread tid holds cols (tid&15)*8+k of node tid>>4
        ss[tid][0] = active ? h0 : 0.f; sq[tid][0] = active ? h0 * h0 : 0.f;
        ss[tid][1] = active ? h1 : 0.f; sq[tid][1] = active ? h1 * h1 : 0.f;
        ss[tid][2] = active ? h2 : 0.f; sq[tid][2] = active ? h2 * h2 : 0.f;
        ss[tid][3] = active ? h3 : 0.f; sq[tid][3] = active ? h3 * h3 : 0.f;
        ss[tid][4] = active ? h4 : 0.f; sq[tid][4] = active ? h4 * h4 : 0.f;
        ss[tid][5] = active ? h5 : 0.f; sq[tid][5] = active ? h5 * h5 : 0.f;
        ss[tid][6] = active ? h6 : 0.f; sq[tid][6] = active ? h6 * h6 : 0.f;
        ss[tid][7] = active ? h7 : 0.f; sq[tid][7] = active ? h7 * h7 : 0.f;
        __syncthreads();
        if (tid < 128) {
            int c = tid >> 3, k = tid & 7;     // col = c*8 + k = tid
            float S = 0.f, Q = 0.f;
#pragma unroll
            for (int g = 0; g < 16; ++g) {
                S += ss[g * 16 + c][k];
                Q += sq[g * 16 + c][k];
            }
            float* pslot = part + (size_t)(blockIdx.x & (CSB - 1)) * 256;
            atomicAdd(&pslot[tid], S);
            atomicAdd(&pslot[128 + tid], Q);
        }
    }
}

// ---------------- reduce partials + alpha/beta (separate launch = free visibility) --
__global__ __launch_bounds__(256) void k_colfin(const float* __restrict__ part,
                                                const float* __restrict__ w,
                                                const float* __restrict__ bb,
                                                const float* __restrict__ ms,
                                                float* __restrict__ alpha,
                                                float* __restrict__ beta, float inv_n) {
    int tid = threadIdx.x;
    float a0 = 0.f, a1 = 0.f, a2 = 0.f, a3 = 0.f;
    for (int b = 0; b < CSB; b += 4) {
        a0 += part[(b + 0) * 256 + tid];
        a1 += part[(b + 1) * 256 + tid];
        a2 += part[(b + 2) * 256 + tid];
        a3 += part[(b + 3) * 256 + tid];
    }
    __shared__ float fin[256];
    fin[tid] = (a0 + a1) + (a2 + a3);
    __syncthreads();
    if (tid < 128) {
        float mean = fin[tid] * inv_n;
        float ex2 = fin[128 + tid] * inv_n;
        float m2 = mean * ms[tid];
        float var = ex2 - 2.f * m2 * mean + m2 * m2;
        float a = w[tid] * rsqrtf(var + 1e-5f);
        alpha[tid] = a;
        beta[tid] = bb[tid] - m2 * a;
    }
}

// ---------------- global_add_pool: 4 blocks/graph, binary search, no atomics -------
__device__ __forceinline__ int lower_bound_i(const int* __restrict__ a, int n, int key) {
    int lo = 0, hi = n;
    while (lo < hi) {
        int mid = (lo + hi) >> 1;
        if (a[mid] < key) lo = mid + 1; else hi = mid;
    }
    return lo;
}

__global__ __launch_bounds__(256) void k_pool(const unsigned short* __restrict__ hb,
                                              const int* __restrict__ batch,
                                              float* __restrict__ pooled4, int n) {
    int g = blockIdx.x >> 2, t4 = blockIdx.x & 3;
    int lo = lower_bound_i(batch, n, g);
    int hi = lower_bound_i(batch, n, g + 1);
    int len = hi - lo;
    int q = (len + 3) >> 2;
    int r0 = lo + t4 * q;
    int r1 = min(r0 + q, hi);
    int c4 = threadIdx.x & 31, rg = threadIdx.x >> 5;
    const ushort4* h4 = (const ushort4*)hb;
    float4 acc = make_float4(0.f, 0.f, 0.f, 0.f);
    for (int r = r0 + rg; r < r1; r += 8) {
        ushort4 hv = h4[(size_t)r * 32 + c4];
        acc.x += f_of_bf16(hv.x);
        acc.y += f_of_bf16(hv.y);
        acc.z += f_of_bf16(hv.z);
        acc.w += f_of_bf16(hv.w);
    }
    __shared__ float4 sred[256];
    sred[threadIdx.x] = acc;
    __syncthreads();
    if (threadIdx.x < 32) {
        float4 S = sred[threadIdx.x];
#pragma unroll
        for (int k = 1; k < 8; ++k) {
            float4 a = sred[threadIdx.x + 32 * k];
            S.x += a.x; S.y += a.y; S.z += a.z; S.w += a.w;
        }
        ((float4*)pooled4)[(t4 * GG + g) * 32 + threadIdx.x] = S;
    }
}

// ---------------- final MLP (sums the 4 pool partials) ----------------
__global__ __launch_bounds__(128) void k_mlp(const float* __restrict__ pooled4,
                                             const float* __restrict__ W1,
                                             const float* __restrict__ b1,
                                             const float* __restrict__ W2,
                                             const float* __restrict__ b2,
                                             float* __restrict__ out) {
    __shared__ float pr[HD];
    __shared__ float zs[HD];
    int g = blockIdx.x, t = threadIdx.x;
    float pv = 0.f;
#pragma unroll
    for (int k = 0; k < 4; ++k) pv += pooled4[(k * GG + g) * HD + t];
    pr[t] = pv;
    __syncthreads();
    float acc = b1[t];
#pragma unroll 8
    for (int k = 0; k < HD; ++k) acc = fmaf(pr[k], W1[k * HD + t], acc);
    zs[t] = leaky(acc, 0.01f);
    __syncthreads();
    if (t < 64) {
        float a2 = b2[t];
#pragma unroll 8
        for (int k = 0; k < HD; ++k) a2 = fmaf(zs[k], W2[k * 64 + t], a2);
        out[g * 64 + t] = a2;
    }
}

extern "C" void kernel_launch(void* const* d_in, const int* in_sizes, int n_in,
                              void* d_out, int out_size, void* d_ws, size_t ws_size,
                              hipStream_t stream) {
    const float* x        = (const float*)d_in[0];
    const int*   ei       = (const int*)d_in[1];
    const int*   batch    = (const int*)d_in[2];
    const float* Ws       = (const float*)d_in[3];
    const float* att_src  = (const float*)d_in[4];
    const float* att_dst  = (const float*)d_in[5];
    const float* conv_bias= (const float*)d_in[6];
    const float* gn_w     = (const float*)d_in[7];
    const float* gn_b     = (const float*)d_in[8];
    const float* gn_ms    = (const float*)d_in[9];
    const float* W1       = (const float*)d_in[10];
    const float* b1       = (const float*)d_in[11];
    const float* W2       = (const float*)d_in[12];
    const float* b2       = (const float*)d_in[13];
    float* out = (float*)d_out;

    const int n = in_sizes[2];       // 100000
    const int e = in_sizes[1] / 2;   // 600000
    const int* src = ei;
    const int* dst = ei + e;
    const int nbk = (n + 511) >> 9;  // 512-node buckets (n <= 262144 for ebuf packing)

    char* ws = (char*)d_ws;
    unsigned short* hWb = (unsigned short*)ws;                    // n*128 bf16
    unsigned short* hb  = hWb + (size_t)n * HD;                   // n*128 bf16
    float* a_s    = (float*)(hb + (size_t)n * HD);                // n
    float* a_d    = a_s + n;                                      // n
    float* alpha  = a_d + n;                                      // 128
    float* beta   = alpha + HD;                                   // 128
    float* pooled4= beta + HD;                                    // 4*GG*128
    float* part   = pooled4 + 4 * GG * HD;                        // 2*CSB*256 (ping-pong)
    unsigned short* Wt = (unsigned short*)(part + 2 * CSB * 256); // 3*128*128
    int* offs     = (int*)(Wt + 3 * 16384);                       // n+1
    int* esrc     = offs + n + 1;                                 // e
    int* ebuf     = esrc + e;                                     // e
    int* bcnt     = ebuf + e;                                     // 513
    int* bbase    = bcnt + 513;                                   // 514
    int* bcur     = bbase + 514;                                  // 513

    float* part0 = part;
    float* part1 = part + CSB * 256;

    // ---- init (weights->bf16 transposed + zero bucket counters + part buffers) ----
    k_init<<<512, 256, 0, stream>>>(Ws, Wt, bcnt, part);
    // ---- bucketed CSR build ----
    k_bcount<<<256, 256, 0, stream>>>(dst, bcnt, e);
    k_bscan<<<1, 512, 0, stream>>>(bcnt, bbase, bcur, offs, nbk, n, e);
    k_part<<<256, 256, 0, stream>>>(src, dst, bcur, ebuf, e);
    k_bscatter<<<nbk, 256, 0, stream>>>(ebuf, bbase, offs, esrc, n);

    // ---- GAT layers ----
    for (int l = 0; l < 3; ++l) {
        if (l == 0) {
            k_gemm_a32<<<(n + 63) / 64, 256, 0, stream>>>(
                x, Wt, att_src, att_dst, hWb, a_s, a_d, n);
        } else {
            k_gemm_a16<<<(n + 63) / 64, 256, 0, stream>>>(
                hb, Wt + l * 16384, att_src + l * HD, att_dst + l * HD,
                alpha, beta, hWb, a_s, a_d, n);
        }
        float* lpart = (l == 0) ? part0 : (l == 1) ? part1 : nullptr;
        k_agg<<<(n + 15) / 16, 256, 0, stream>>>(hWb, offs, esrc, a_s, a_d,
                                                 conv_bias + l * HD, hb, lpart, n);
        if (l < 2) {
            k_colfin<<<1, 256, 0, stream>>>(lpart, gn_w + l * HD, gn_b + l * HD,
                                            gn_ms + l * HD, alpha, beta, 1.0f / n);
        }
    }

    // ---- pool + MLP ----
    k_pool<<<4 * GG, 256, 0, stream>>>(hb, batch, pooled4, n);
    k_mlp<<<GG, HD, 0, stream>>>(pooled4, W1, b1, W2, b2, out);
}